// Round 2
// baseline (52.936 us; speedup 1.0000x reference)
//
#include <hip/hip_runtime.h>
#include <hip/hip_bf16.h>

// out[i] = mask[i] ? x[i] * (1/(1-0.5)) : 0
// x: float32, mask: boolean passed as int32 by the harness.
// Memory-bound elementwise: vectorized 16B/lane loads, grid-stride loop.

__global__ void __launch_bounds__(256)
dropout_vec4_kernel(const float4* __restrict__ x4,
                    const int4* __restrict__ m4,
                    float4* __restrict__ o4,
                    int n4)
{
    const float scale = 2.0f;  // 1 / (1 - 0.5)
    int idx = blockIdx.x * blockDim.x + threadIdx.x;
    int stride = gridDim.x * blockDim.x;
    for (int i = idx; i < n4; i += stride) {
        float4 xv = x4[i];
        int4   mv = m4[i];
        float4 ov;
        ov.x = mv.x ? xv.x * scale : 0.0f;
        ov.y = mv.y ? xv.y * scale : 0.0f;
        ov.z = mv.z ? xv.z * scale : 0.0f;
        ov.w = mv.w ? xv.w * scale : 0.0f;
        o4[i] = ov;
    }
}

// Scalar tail (not expected to run: 25,690,112 % 4 == 0, but keep it correct
// for any shape).
__global__ void __launch_bounds__(256)
dropout_tail_kernel(const float* __restrict__ x,
                    const int* __restrict__ m,
                    float* __restrict__ o,
                    int start, int n)
{
    int i = start + blockIdx.x * blockDim.x + threadIdx.x;
    if (i < n) {
        o[i] = m[i] ? x[i] * 2.0f : 0.0f;
    }
}

extern "C" void kernel_launch(void* const* d_in, const int* in_sizes, int n_in,
                              void* d_out, int out_size, void* d_ws, size_t ws_size,
                              hipStream_t stream)
{
    const float* x = (const float*)d_in[0];
    const int*   m = (const int*)d_in[1];
    float*       o = (float*)d_out;

    int n  = out_size;      // 25,690,112
    int n4 = n / 4;

    const int block = 256;
    // Cap grid at ~8 blocks/CU * 256 CUs; grid-stride the rest.
    int grid = (n4 + block - 1) / block;
    if (grid > 2048) grid = 2048;
    if (grid < 1) grid = 1;

    dropout_vec4_kernel<<<grid, block, 0, stream>>>(
        (const float4*)x, (const int4*)m, (float4*)o, n4);

    int rem = n - n4 * 4;
    if (rem > 0) {
        int tgrid = (rem + block - 1) / block;
        dropout_tail_kernel<<<tgrid, block, 0, stream>>>(x, m, o, n4 * 4, n);
    }
}